// Round 5
// baseline (416.350 us; speedup 1.0000x reference)
//
#include <hip/hip_runtime.h>
#include <hip/hip_bf16.h>

typedef unsigned int   uint;
typedef unsigned short ushort;
typedef short bf16x8 __attribute__((ext_vector_type(8)));
typedef float f32x4  __attribute__((ext_vector_type(4)));
typedef float f4u    __attribute__((ext_vector_type(4), aligned(4)));  // align-4 float4

// Problem constants
constexpr int Bm   = 512;   // molecules
constexpr int Aa   = 128;   // atoms / molecule
constexpr int Ee   = 256;   // directed bonds / molecule
constexpr int Kk   = 6;     // incoming gathered
constexpr int AFD  = 133;
constexpr int FD   = 147;   // 133+14
constexpr int Hh   = 128;
constexpr int CATD = 261;   // 133+128
constexpr int KWI  = 160;   // Wi_b row stride (147 real + 13 zero)
constexpr int KWO  = 288;   // Wo_b row stride: [0,133) atomf cols, [133,160) zero, [160,288) m2a

// ---- bf16 helpers ----------------------------------------------------------
__device__ __forceinline__ ushort f2b(float f) {
    uint u = __float_as_uint(f);
    u += 0x7FFFu + ((u >> 16) & 1u);
    return (ushort)(u >> 16);
}
__device__ __forceinline__ uint f2b2(float x, float y) {
    return (uint)f2b(x) | ((uint)f2b(y) << 16);
}
__device__ __forceinline__ float2 b2f2(uint p) {
    float2 r;
    r.x = __uint_as_float(p << 16);
    r.y = __uint_as_float(p & 0xFFFF0000u);
    return r;
}
// relu on 2 packed bf16 (zero the halves whose sign bit is set)
__device__ __forceinline__ uint relu2u(uint u) {
    uint neg  = u & 0x80008000u;
    uint mask = (neg >> 15) * 0xFFFFu;
    return u & ~mask;
}
__device__ __forceinline__ bf16x8 cvt8(f4u a, f4u b) {
    union { uint4 u; bf16x8 v; } r;
    r.u.x = f2b2(a.x, a.y); r.u.y = f2b2(a.z, a.w);
    r.u.z = f2b2(b.x, b.y); r.u.w = f2b2(b.z, b.w);
    return r.v;
}
__device__ __forceinline__ bf16x8 zero8() {
    union { uint4 u; bf16x8 v; } r;
    r.u.x = r.u.y = r.u.z = r.u.w = 0u;
    return r.v;
}
__device__ __forceinline__ void acc_octet(float s[8], uint4 m8) {
    uint u0 = relu2u(m8.x), u1 = relu2u(m8.y), u2 = relu2u(m8.z), u3 = relu2u(m8.w);
    float2 a0 = b2f2(u0); s[0] += a0.x; s[1] += a0.y;
    float2 a1 = b2f2(u1); s[2] += a1.x; s[3] += a1.y;
    float2 a2 = b2f2(u2); s[4] += a2.x; s[5] += a2.y;
    float2 a3 = b2f2(u3); s[6] += a3.x; s[7] += a3.y;
}
__device__ __forceinline__ bf16x8 pack8(const float s[8]) {
    union { uint4 u; bf16x8 v; } r;
    r.u.x = f2b2(s[0], s[1]); r.u.y = f2b2(s[2], s[3]);
    r.u.z = f2b2(s[4], s[5]); r.u.w = f2b2(s[6], s[7]);
    return r.v;
}
// XOR-swizzled sMsg address (elements). Row-major 256x128, octet ^= row&7.
__device__ __forceinline__ int swz(int row, int col) {
    return row * 128 + ((((col >> 3) ^ (row & 7))) << 3) + (col & 7);
}

// ---------------------------------------------------------------------------
// Weight prep: fp32 -> padded bf16 (tiny, L2-resident afterwards)
// ---------------------------------------------------------------------------
__global__ __launch_bounds__(256) void k_prep_w(const float* __restrict__ Wi,
                                                const float* __restrict__ Wh,
                                                const float* __restrict__ Wo,
                                                ushort* __restrict__ Wi_b,
                                                ushort* __restrict__ Wh_b,
                                                ushort* __restrict__ Wo_b) {
    const int h = blockIdx.x, t = threadIdx.x;
    for (int c = t; c < KWI; c += 256)
        Wi_b[h * KWI + c] = f2b(c < FD ? Wi[h * FD + c] : 0.f);
    for (int c = t; c < Hh; c += 256)
        Wh_b[h * Hh + c] = f2b(Wh[h * Hh + c]);
    for (int c = t; c < KWO; c += 256) {
        float v = 0.f;
        if (c < AFD)       v = Wo[h * CATD + c];
        else if (c >= 160) v = Wo[h * CATD + AFD + (c - 160)];
        Wo_b[h * KWO + c] = f2b(v);
    }
}

// ---------------------------------------------------------------------------
// Fused DMPNN: one block = one molecule, 1024 threads (16 waves).
// Phases 1-2: wave w owns bond rows [w*16, w*16+16): acc[8] (32 VGPR),
// inp skip-connection kept packed-bf16 in registers (16 VGPR).
// Phase 3: wave w = (strip, col-half): 16 atoms x 64 cols, racc[4].
// msg lives in XOR-swizzled LDS (64 KB); indices live in registers; weights
// bf16 from global (L1/L2-resident).
// ---------------------------------------------------------------------------
__global__ __launch_bounds__(1024) void k_fused(
        const float* __restrict__ fini, const int* __restrict__ mapping,
        const int* __restrict__ a2ib, const float* __restrict__ atomf,
        const ushort* __restrict__ Wi_b, const ushort* __restrict__ Wh_b,
        const ushort* __restrict__ Wo_b, const float* __restrict__ bo,
        const int* __restrict__ mol_lens, const int* __restrict__ pfx,
        float* __restrict__ out) {
    __shared__ ushort sMsg[256 * 128];     // 64 KB, XOR-swizzled

    const int tid  = threadIdx.x;
    const int mol  = blockIdx.x;
    const int wave = tid >> 6, lane = tid & 63;
    const int l15  = lane & 15, quad = lane >> 4;

    // Row ownerships + index registers
    const int mrow = wave * 16 + l15;                  // bond row (phases 1-2)
    const int aw   = wave & 7, ch = wave >> 3;         // phase-3 strip / col-half
    const int arow = aw * 16 + l15;                    // atom row (phase 3)
    int myMap[Kk], myA2[Kk];
#pragma unroll
    for (int k = 0; k < Kk; ++k)
        myMap[k] = mapping[((size_t)mol * Ee + mrow) * Kk + k];
#pragma unroll
    for (int k = 0; k < Kk; ++k)
        myA2[k] = a2ib[((size_t)mol * Aa + arow) * Kk + k];

    // ---------------- Phase 1: inp = fini @ Wi^T (K=147 -> 160) ------------
    f32x4 acc[8] = {};
    const float* frow = fini + ((size_t)mol * Ee + mrow) * FD;
#pragma unroll
    for (int ks = 0; ks < 5; ++ks) {
        bf16x8 af;
        const float* p = frow + ks * 32 + quad * 8;
        if (ks < 4 || quad < 2) {
            af = cvt8(*(const f4u*)p, *(const f4u*)(p + 4));
        } else if (quad == 2) {             // cols 144..146 real, rest zero
            union { uint4 u; bf16x8 v; } r;
            r.u.x = f2b2(p[0], p[1]);
            r.u.y = f2b2(p[2], 0.f);
            r.u.z = 0u; r.u.w = 0u;
            af = r.v;
        } else {
            af = zero8();
        }
#pragma unroll
        for (int j = 0; j < 8; ++j) {
            bf16x8 bf = *(const bf16x8*)&Wi_b[(j * 16 + l15) * KWI + ks * 32 + quad * 8];
            acc[j] = __builtin_amdgcn_mfma_f32_16x16x32_bf16(af, bf, acc[j], 0, 0, 0);
        }
    }

    // Keep inp packed bf16 in registers (C-layout); write relu(inp) to sMsg.
    uint2 inpP[8];
#pragma unroll
    for (int j = 0; j < 8; ++j) {
        inpP[j].x = f2b2(acc[j][0], acc[j][1]);
        inpP[j].y = f2b2(acc[j][2], acc[j][3]);
        const int col = j * 16 + l15;
#pragma unroll
        for (int reg = 0; reg < 4; ++reg) {
            const int row = wave * 16 + quad * 4 + reg;
            float v = acc[j][reg];
            sMsg[swz(row, col)] = f2b(v > 0.f ? v : 0.f);
        }
    }
    __syncthreads();

    // ---------------- Phase 2: two hops -------------------------------------
#pragma unroll 1
    for (int hop = 0; hop < 2; ++hop) {
#pragma unroll
        for (int j = 0; j < 8; ++j) acc[j] = f32x4{0.f, 0.f, 0.f, 0.f};

#pragma unroll
        for (int ks = 0; ks < 4; ++ks) {
            const int g = ks * 4 + quad;
            float s[8] = {0.f, 0.f, 0.f, 0.f, 0.f, 0.f, 0.f, 0.f};
#pragma unroll
            for (int kk = 0; kk < Kk; ++kk) {
                const int r = myMap[kk];
                uint4 m8 = *(const uint4*)&sMsg[r * 128 + ((g ^ (r & 7)) << 3)];
                acc_octet(s, m8);
            }
            bf16x8 af = pack8(s);
#pragma unroll
            for (int j = 0; j < 8; ++j) {
                bf16x8 bf = *(const bf16x8*)&Wh_b[(j * 16 + l15) * Hh + ks * 32 + quad * 8];
                acc[j] = __builtin_amdgcn_mfma_f32_16x16x32_bf16(af, bf, acc[j], 0, 0, 0);
            }
        }
        __syncthreads();                    // all gathers done before overwrite
#pragma unroll
        for (int j = 0; j < 8; ++j) {
            const int col = j * 16 + l15;
            float2 p01 = b2f2(inpP[j].x);
            float2 p23 = b2f2(inpP[j].y);
            float v[4] = {p01.x + acc[j][0], p01.y + acc[j][1],
                          p23.x + acc[j][2], p23.y + acc[j][3]};
#pragma unroll
            for (int reg = 0; reg < 4; ++reg) {
                const int row = wave * 16 + quad * 4 + reg;
                sMsg[swz(row, col)] = f2b(v[reg] > 0.f ? v[reg] : 0.f);
            }
        }
        __syncthreads();
    }

    // ---------------- Phase 3: readout --------------------------------------
    // K-space: [0,133) atomf (padded to 160), [160,288) m2a gather from sMsg.
    // Wave (aw, ch): 16 atoms x 64 cols; j4 = ch*4 + jj.
    f32x4 racc[4] = {};
    const float* arow_p = atomf + ((size_t)mol * Aa + arow) * AFD;
#pragma unroll
    for (int ks = 0; ks < 9; ++ks) {
        bf16x8 af;
        if (ks < 4) {                               // atomf cols 0..127
            const float* p = arow_p + ks * 32 + quad * 8;
            af = cvt8(*(const f4u*)p, *(const f4u*)(p + 4));
        } else if (ks == 4) {                       // cols 128..132 real
            if (quad == 0) {
                const float* p = arow_p + 128;
                union { uint4 u; bf16x8 v; } r;
                r.u.x = f2b2(p[0], p[1]);
                r.u.y = f2b2(p[2], p[3]);
                r.u.z = f2b2(p[4], 0.f);
                r.u.w = 0u;
                af = r.v;
            } else {
                af = zero8();
            }
        } else {                                    // m2a gather
            const int g = (ks - 5) * 4 + quad;
            float s[8] = {0.f, 0.f, 0.f, 0.f, 0.f, 0.f, 0.f, 0.f};
#pragma unroll
            for (int kk = 0; kk < Kk; ++kk) {
                const int r = myA2[kk];
                uint4 m8 = *(const uint4*)&sMsg[r * 128 + ((g ^ (r & 7)) << 3)];
                acc_octet(s, m8);
            }
            af = pack8(s);
        }
#pragma unroll
        for (int jj = 0; jj < 4; ++jj) {
            const int j4 = ch * 4 + jj;
            bf16x8 bf = *(const bf16x8*)&Wo_b[(j4 * 16 + l15) * KWO + ks * 32 + quad * 8];
            racc[jj] = __builtin_amdgcn_mfma_f32_16x16x32_bf16(af, bf, racc[jj], 0, 0, 0);
        }
    }

    const int len  = mol_lens[mol];
    const int base = pfx[mol];
#pragma unroll
    for (int jj = 0; jj < 4; ++jj) {
        const int col = (ch * 4 + jj) * 16 + l15;
        const float bj = bo[col];
#pragma unroll
        for (int reg = 0; reg < 4; ++reg) {
            const int ar = aw * 16 + quad * 4 + reg;
            if (ar < len) {
                float v = racc[jj][reg] + bj;
                out[(size_t)(base + ar) * Hh + col] = v > 0.f ? v : 0.f;
            }
        }
    }
}

// ---------------------------------------------------------------------------
__global__ __launch_bounds__(512) void k_scan(const int* __restrict__ ml,
                                              int* __restrict__ pfx) {
    __shared__ int s[512];
    int t = threadIdx.x;
    s[t] = ml[t];
    __syncthreads();
    for (int off = 1; off < 512; off <<= 1) {
        int v = (t >= off) ? s[t - off] : 0;
        __syncthreads();
        s[t] += v;
        __syncthreads();
    }
    pfx[t + 1] = s[t];
    if (t == 0) pfx[0] = 0;
}

__global__ __launch_bounds__(128) void k_cmask(const int* __restrict__ ml,
                                               float* __restrict__ cmask) {
    int b = blockIdx.x, t = threadIdx.x;
    cmask[b * Aa + t] = (t < ml[b]) ? 1.0f : 0.0f;
}

// ---------------------------------------------------------------------------
extern "C" void kernel_launch(void* const* d_in, const int* in_sizes, int n_in,
                              void* d_out, int out_size, void* d_ws, size_t ws_size,
                              hipStream_t stream) {
    const float* atom_feature = (const float*)d_in[0];
    const float* f_ini        = (const float*)d_in[1];
    const int*   a2ib         = (const int*)d_in[2];
    const int*   mapping      = (const int*)d_in[3];
    const int*   mol_lens     = (const int*)d_in[5];
    const float* Wi           = (const float*)d_in[6];
    const float* Wh           = (const float*)d_in[7];
    const float* Wo           = (const float*)d_in[8];
    const float* bo           = (const float*)d_in[9];
    float* out = (float*)d_out;

    // Workspace: only prepped weights + prefix sums (~0.2 MB)
    ushort* Wi_b = (ushort*)d_ws;
    ushort* Wh_b = Wi_b + 128 * KWI;
    ushort* Wo_b = Wh_b + 128 * Hh;
    int*    pfx  = (int*)(Wo_b + 128 * KWO);

    float* cmask = out + ((size_t)out_size - (size_t)Bm * Aa);

    k_prep_w<<<128, 256, 0, stream>>>(Wi, Wh, Wo, Wi_b, Wh_b, Wo_b);
    k_scan  <<<1, 512, 0, stream>>>(mol_lens, pfx);
    k_cmask <<<Bm, 128, 0, stream>>>(mol_lens, cmask);
    k_fused <<<Bm, 1024, 0, stream>>>(f_ini, mapping, a2ib, atom_feature,
                                      Wi_b, Wh_b, Wo_b, bo, mol_lens, pfx, out);
}

// Round 6
// 397.697 us; speedup vs baseline: 1.0469x; 1.0469x over previous
//
#include <hip/hip_runtime.h>
#include <hip/hip_bf16.h>

typedef unsigned int   uint;
typedef unsigned short ushort;
typedef short bf16x8 __attribute__((ext_vector_type(8)));
typedef float f32x4  __attribute__((ext_vector_type(4)));
typedef float f4u    __attribute__((ext_vector_type(4), aligned(4)));  // align-4 float4

// Problem constants
constexpr int Bm   = 512;   // molecules
constexpr int Aa   = 128;   // atoms / molecule
constexpr int Ee   = 256;   // directed bonds / molecule
constexpr int Kk   = 6;     // incoming gathered
constexpr int AFD  = 133;
constexpr int FD   = 147;   // 133+14
constexpr int Hh   = 128;
constexpr int CATD = 261;   // 133+128
constexpr int KWI  = 160;   // Wi_b row stride (147 real + 13 zero)
constexpr int KWO  = 288;   // Wo_b row stride: [0,133) atomf cols, [133,160) zero, [160,288) m2a

// ---- bf16 helpers ----------------------------------------------------------
__device__ __forceinline__ ushort f2b(float f) {
    uint u = __float_as_uint(f);
    u += 0x7FFFu + ((u >> 16) & 1u);
    return (ushort)(u >> 16);
}
__device__ __forceinline__ uint f2b2(float x, float y) {
    return (uint)f2b(x) | ((uint)f2b(y) << 16);
}
__device__ __forceinline__ float2 b2f2(uint p) {
    float2 r;
    r.x = __uint_as_float(p << 16);
    r.y = __uint_as_float(p & 0xFFFF0000u);
    return r;
}
// relu on 2 packed bf16 (zero the halves whose sign bit is set)
__device__ __forceinline__ uint relu2u(uint u) {
    uint neg  = u & 0x80008000u;
    uint mask = (neg >> 15) * 0xFFFFu;
    return u & ~mask;
}
__device__ __forceinline__ bf16x8 cvt8(f4u a, f4u b) {
    union { uint4 u; bf16x8 v; } r;
    r.u.x = f2b2(a.x, a.y); r.u.y = f2b2(a.z, a.w);
    r.u.z = f2b2(b.x, b.y); r.u.w = f2b2(b.z, b.w);
    return r.v;
}
__device__ __forceinline__ bf16x8 zero8() {
    union { uint4 u; bf16x8 v; } r;
    r.u.x = r.u.y = r.u.z = r.u.w = 0u;
    return r.v;
}
__device__ __forceinline__ void acc_octet(float s[8], uint4 m8) {
    uint u0 = relu2u(m8.x), u1 = relu2u(m8.y), u2 = relu2u(m8.z), u3 = relu2u(m8.w);
    float2 a0 = b2f2(u0); s[0] += a0.x; s[1] += a0.y;
    float2 a1 = b2f2(u1); s[2] += a1.x; s[3] += a1.y;
    float2 a2 = b2f2(u2); s[4] += a2.x; s[5] += a2.y;
    float2 a3 = b2f2(u3); s[6] += a3.x; s[7] += a3.y;
}
__device__ __forceinline__ bf16x8 pack8(const float s[8]) {
    union { uint4 u; bf16x8 v; } r;
    r.u.x = f2b2(s[0], s[1]); r.u.y = f2b2(s[2], s[3]);
    r.u.z = f2b2(s[4], s[5]); r.u.w = f2b2(s[6], s[7]);
    return r.v;
}
// XOR-swizzled sMsg address (elements). Row-major 256x128, octet ^= row&7.
__device__ __forceinline__ int swz(int row, int col) {
    return row * 128 + ((((col >> 3) ^ (row & 7))) << 3) + (col & 7);
}

// ---------------------------------------------------------------------------
// Weight prep: fp32 -> padded bf16 (tiny, L2-resident afterwards)
// ---------------------------------------------------------------------------
__global__ __launch_bounds__(256) void k_prep_w(const float* __restrict__ Wi,
                                                const float* __restrict__ Wh,
                                                const float* __restrict__ Wo,
                                                ushort* __restrict__ Wi_b,
                                                ushort* __restrict__ Wh_b,
                                                ushort* __restrict__ Wo_b) {
    const int h = blockIdx.x, t = threadIdx.x;
    for (int c = t; c < KWI; c += 256)
        Wi_b[h * KWI + c] = f2b(c < FD ? Wi[h * FD + c] : 0.f);
    for (int c = t; c < Hh; c += 256)
        Wh_b[h * Hh + c] = f2b(Wh[h * Hh + c]);
    for (int c = t; c < KWO; c += 256) {
        float v = 0.f;
        if (c < AFD)       v = Wo[h * CATD + c];
        else if (c >= 160) v = Wo[h * CATD + AFD + (c - 160)];
        Wo_b[h * KWO + c] = f2b(v);
    }
}

// ---------------------------------------------------------------------------
// Fused DMPNN: one block = one molecule, 1024 threads (16 waves).
// __launch_bounds__(1024, 4): exactly 1 block/CU resident -> 128-VGPR cap.
// (Round 5's failure: without the min-waves arg the compiler targeted
//  2 blocks/CU -> 64 VGPRs -> ~310 MB of scratch spill traffic.)
// Phases 1-2: wave w owns bond rows [w*16, w*16+16): acc[8] (32 VGPR),
// inp skip kept packed-bf16 in registers (16 VGPR).
// Phase 3: wave w = (strip, col-half): 16 atoms x 64 cols, racc[4].
// msg lives in XOR-swizzled LDS (64 KB); indices in registers; weights bf16
// from global (L1/L2-resident).
// ---------------------------------------------------------------------------
__global__ __launch_bounds__(1024, 4) void k_fused(
        const float* __restrict__ fini, const int* __restrict__ mapping,
        const int* __restrict__ a2ib, const float* __restrict__ atomf,
        const ushort* __restrict__ Wi_b, const ushort* __restrict__ Wh_b,
        const ushort* __restrict__ Wo_b, const float* __restrict__ bo,
        const int* __restrict__ mol_lens, const int* __restrict__ pfx,
        float* __restrict__ out) {
    __shared__ ushort sMsg[256 * 128];     // 64 KB, XOR-swizzled

    const int tid  = threadIdx.x;
    const int mol  = blockIdx.x;
    const int wave = tid >> 6, lane = tid & 63;
    const int l15  = lane & 15, quad = lane >> 4;

    // Row ownership + gather indices for phases 1-2
    const int mrow = wave * 16 + l15;                  // bond row
    int myMap[Kk];
#pragma unroll
    for (int k = 0; k < Kk; ++k)
        myMap[k] = mapping[((size_t)mol * Ee + mrow) * Kk + k];

    // ---------------- Phase 1: inp = fini @ Wi^T (K=147 -> 160) ------------
    f32x4 acc[8] = {};
    const float* frow = fini + ((size_t)mol * Ee + mrow) * FD;
#pragma unroll
    for (int ks = 0; ks < 5; ++ks) {
        bf16x8 af;
        const float* p = frow + ks * 32 + quad * 8;
        if (ks < 4 || quad < 2) {
            af = cvt8(*(const f4u*)p, *(const f4u*)(p + 4));
        } else if (quad == 2) {             // cols 144..146 real, rest zero
            union { uint4 u; bf16x8 v; } r;
            r.u.x = f2b2(p[0], p[1]);
            r.u.y = f2b2(p[2], 0.f);
            r.u.z = 0u; r.u.w = 0u;
            af = r.v;
        } else {
            af = zero8();
        }
#pragma unroll
        for (int j = 0; j < 8; ++j) {
            bf16x8 bf = *(const bf16x8*)&Wi_b[(j * 16 + l15) * KWI + ks * 32 + quad * 8];
            acc[j] = __builtin_amdgcn_mfma_f32_16x16x32_bf16(af, bf, acc[j], 0, 0, 0);
        }
    }

    // Keep inp packed bf16 in registers (C-layout); write relu(inp) to sMsg.
    uint2 inpP[8];
#pragma unroll
    for (int j = 0; j < 8; ++j) {
        inpP[j].x = f2b2(acc[j][0], acc[j][1]);
        inpP[j].y = f2b2(acc[j][2], acc[j][3]);
        const int col = j * 16 + l15;
#pragma unroll
        for (int reg = 0; reg < 4; ++reg) {
            const int row = wave * 16 + quad * 4 + reg;
            float v = acc[j][reg];
            sMsg[swz(row, col)] = f2b(v > 0.f ? v : 0.f);
        }
    }
    __syncthreads();

    // ---------------- Phase 2: two hops -------------------------------------
#pragma unroll 1
    for (int hop = 0; hop < 2; ++hop) {
#pragma unroll
        for (int j = 0; j < 8; ++j) acc[j] = f32x4{0.f, 0.f, 0.f, 0.f};

#pragma unroll
        for (int ks = 0; ks < 4; ++ks) {
            const int g = ks * 4 + quad;
            float s[8] = {0.f, 0.f, 0.f, 0.f, 0.f, 0.f, 0.f, 0.f};
#pragma unroll
            for (int kk = 0; kk < Kk; ++kk) {
                const int r = myMap[kk];
                uint4 m8 = *(const uint4*)&sMsg[r * 128 + ((g ^ (r & 7)) << 3)];
                acc_octet(s, m8);
            }
            bf16x8 af = pack8(s);
#pragma unroll
            for (int j = 0; j < 8; ++j) {
                bf16x8 bf = *(const bf16x8*)&Wh_b[(j * 16 + l15) * Hh + ks * 32 + quad * 8];
                acc[j] = __builtin_amdgcn_mfma_f32_16x16x32_bf16(af, bf, acc[j], 0, 0, 0);
            }
        }
        __syncthreads();                    // all gathers done before overwrite
#pragma unroll
        for (int j = 0; j < 8; ++j) {
            const int col = j * 16 + l15;
            float2 p01 = b2f2(inpP[j].x);
            float2 p23 = b2f2(inpP[j].y);
            float v[4] = {p01.x + acc[j][0], p01.y + acc[j][1],
                          p23.x + acc[j][2], p23.y + acc[j][3]};
#pragma unroll
            for (int reg = 0; reg < 4; ++reg) {
                const int row = wave * 16 + quad * 4 + reg;
                sMsg[swz(row, col)] = f2b(v[reg] > 0.f ? v[reg] : 0.f);
            }
        }
        __syncthreads();
    }

    // ---------------- Phase 3: readout --------------------------------------
    // K-space: [0,133) atomf (padded to 160), [160,288) m2a gather from sMsg.
    // Wave (aw, ch): 16 atoms x 64 cols; j4 = ch*4 + jj.
    const int aw   = wave & 7, ch = wave >> 3;
    const int arow = aw * 16 + l15;                    // atom row
    int myA2[Kk];                                      // loaded late (live-range)
#pragma unroll
    for (int k = 0; k < Kk; ++k)
        myA2[k] = a2ib[((size_t)mol * Aa + arow) * Kk + k];

    f32x4 racc[4] = {};
    const float* arow_p = atomf + ((size_t)mol * Aa + arow) * AFD;
#pragma unroll
    for (int ks = 0; ks < 9; ++ks) {
        bf16x8 af;
        if (ks < 4) {                               // atomf cols 0..127
            const float* p = arow_p + ks * 32 + quad * 8;
            af = cvt8(*(const f4u*)p, *(const f4u*)(p + 4));
        } else if (ks == 4) {                       // cols 128..132 real
            if (quad == 0) {
                const float* p = arow_p + 128;
                union { uint4 u; bf16x8 v; } r;
                r.u.x = f2b2(p[0], p[1]);
                r.u.y = f2b2(p[2], p[3]);
                r.u.z = f2b2(p[4], 0.f);
                r.u.w = 0u;
                af = r.v;
            } else {
                af = zero8();
            }
        } else {                                    // m2a gather
            const int g = (ks - 5) * 4 + quad;
            float s[8] = {0.f, 0.f, 0.f, 0.f, 0.f, 0.f, 0.f, 0.f};
#pragma unroll
            for (int kk = 0; kk < Kk; ++kk) {
                const int r = myA2[kk];
                uint4 m8 = *(const uint4*)&sMsg[r * 128 + ((g ^ (r & 7)) << 3)];
                acc_octet(s, m8);
            }
            af = pack8(s);
        }
#pragma unroll
        for (int jj = 0; jj < 4; ++jj) {
            const int j4 = ch * 4 + jj;
            bf16x8 bf = *(const bf16x8*)&Wo_b[(j4 * 16 + l15) * KWO + ks * 32 + quad * 8];
            racc[jj] = __builtin_amdgcn_mfma_f32_16x16x32_bf16(af, bf, racc[jj], 0, 0, 0);
        }
    }

    const int len  = mol_lens[mol];
    const int base = pfx[mol];
#pragma unroll
    for (int jj = 0; jj < 4; ++jj) {
        const int col = (ch * 4 + jj) * 16 + l15;
        const float bj = bo[col];
#pragma unroll
        for (int reg = 0; reg < 4; ++reg) {
            const int ar = aw * 16 + quad * 4 + reg;
            if (ar < len) {
                float v = racc[jj][reg] + bj;
                out[(size_t)(base + ar) * Hh + col] = v > 0.f ? v : 0.f;
            }
        }
    }
}

// ---------------------------------------------------------------------------
__global__ __launch_bounds__(512) void k_scan(const int* __restrict__ ml,
                                              int* __restrict__ pfx) {
    __shared__ int s[512];
    int t = threadIdx.x;
    s[t] = ml[t];
    __syncthreads();
    for (int off = 1; off < 512; off <<= 1) {
        int v = (t >= off) ? s[t - off] : 0;
        __syncthreads();
        s[t] += v;
        __syncthreads();
    }
    pfx[t + 1] = s[t];
    if (t == 0) pfx[0] = 0;
}

__global__ __launch_bounds__(128) void k_cmask(const int* __restrict__ ml,
                                               float* __restrict__ cmask) {
    int b = blockIdx.x, t = threadIdx.x;
    cmask[b * Aa + t] = (t < ml[b]) ? 1.0f : 0.0f;
}

// ---------------------------------------------------------------------------
extern "C" void kernel_launch(void* const* d_in, const int* in_sizes, int n_in,
                              void* d_out, int out_size, void* d_ws, size_t ws_size,
                              hipStream_t stream) {
    const float* atom_feature = (const float*)d_in[0];
    const float* f_ini        = (const float*)d_in[1];
    const int*   a2ib         = (const int*)d_in[2];
    const int*   mapping      = (const int*)d_in[3];
    const int*   mol_lens     = (const int*)d_in[5];
    const float* Wi           = (const float*)d_in[6];
    const float* Wh           = (const float*)d_in[7];
    const float* Wo           = (const float*)d_in[8];
    const float* bo           = (const float*)d_in[9];
    float* out = (float*)d_out;

    // Workspace: only prepped weights + prefix sums (~0.2 MB)
    ushort* Wi_b = (ushort*)d_ws;
    ushort* Wh_b = Wi_b + 128 * KWI;
    ushort* Wo_b = Wh_b + 128 * Hh;
    int*    pfx  = (int*)(Wo_b + 128 * KWO);

    float* cmask = out + ((size_t)out_size - (size_t)Bm * Aa);

    k_prep_w<<<128, 256, 0, stream>>>(Wi, Wh, Wo, Wi_b, Wh_b, Wo_b);
    k_scan  <<<1, 512, 0, stream>>>(mol_lens, pfx);
    k_cmask <<<Bm, 128, 0, stream>>>(mol_lens, cmask);
    k_fused <<<Bm, 1024, 0, stream>>>(f_ini, mapping, a2ib, atom_feature,
                                      Wi_b, Wh_b, Wo_b, bo, mol_lens, pfx, out);
}

// Round 7
// 395.940 us; speedup vs baseline: 1.0515x; 1.0044x over previous
//
#include <hip/hip_runtime.h>
#include <hip/hip_bf16.h>

typedef unsigned int   uint;
typedef unsigned short ushort;
typedef short bf16x8 __attribute__((ext_vector_type(8)));
typedef float f32x4  __attribute__((ext_vector_type(4)));
typedef float f4u    __attribute__((ext_vector_type(4), aligned(4)));  // align-4 float4

// Problem constants
constexpr int Bm   = 512;   // molecules
constexpr int Aa   = 128;   // atoms / molecule
constexpr int Ee   = 256;   // directed bonds / molecule
constexpr int Kk   = 6;     // incoming gathered
constexpr int AFD  = 133;
constexpr int FD   = 147;   // 133+14
constexpr int Hh   = 128;
constexpr int CATD = 261;   // 133+128
constexpr int KWI  = 160;   // Wi_b row stride (147 real + 13 zero)
constexpr int KWO  = 288;   // Wo_b row stride: [0,133) atomf cols, [133,160) zero, [160,288) m2a

// ---- bf16 helpers ----------------------------------------------------------
__device__ __forceinline__ ushort f2b(float f) {
    uint u = __float_as_uint(f);
    u += 0x7FFFu + ((u >> 16) & 1u);
    return (ushort)(u >> 16);
}
__device__ __forceinline__ uint f2b2(float x, float y) {
    return (uint)f2b(x) | ((uint)f2b(y) << 16);
}
__device__ __forceinline__ float2 b2f2(uint p) {
    float2 r;
    r.x = __uint_as_float(p << 16);
    r.y = __uint_as_float(p & 0xFFFF0000u);
    return r;
}
// relu on 2 packed bf16 (zero the halves whose sign bit is set)
__device__ __forceinline__ uint relu2u(uint u) {
    uint neg  = u & 0x80008000u;
    uint mask = (neg >> 15) * 0xFFFFu;
    return u & ~mask;
}
__device__ __forceinline__ bf16x8 cvt8(f4u a, f4u b) {
    union { uint4 u; bf16x8 v; } r;
    r.u.x = f2b2(a.x, a.y); r.u.y = f2b2(a.z, a.w);
    r.u.z = f2b2(b.x, b.y); r.u.w = f2b2(b.z, b.w);
    return r.v;
}
__device__ __forceinline__ bf16x8 zero8() {
    union { uint4 u; bf16x8 v; } r;
    r.u.x = r.u.y = r.u.z = r.u.w = 0u;
    return r.v;
}
__device__ __forceinline__ void acc_octet(float s[8], uint4 m8) {
    uint u0 = relu2u(m8.x), u1 = relu2u(m8.y), u2 = relu2u(m8.z), u3 = relu2u(m8.w);
    float2 a0 = b2f2(u0); s[0] += a0.x; s[1] += a0.y;
    float2 a1 = b2f2(u1); s[2] += a1.x; s[3] += a1.y;
    float2 a2 = b2f2(u2); s[4] += a2.x; s[5] += a2.y;
    float2 a3 = b2f2(u3); s[6] += a3.x; s[7] += a3.y;
}
__device__ __forceinline__ bf16x8 pack8(const float s[8]) {
    union { uint4 u; bf16x8 v; } r;
    r.u.x = f2b2(s[0], s[1]); r.u.y = f2b2(s[2], s[3]);
    r.u.z = f2b2(s[4], s[5]); r.u.w = f2b2(s[6], s[7]);
    return r.v;
}
// XOR-swizzled sMsg address (elements). Row-major 256x128, octet ^= row&7.
__device__ __forceinline__ int swz(int row, int col) {
    return row * 128 + ((((col >> 3) ^ (row & 7))) << 3) + (col & 7);
}

// ---------------------------------------------------------------------------
// Weight prep: fp32 -> padded bf16 (tiny, L2-resident afterwards)
// ---------------------------------------------------------------------------
__global__ __launch_bounds__(256) void k_prep_w(const float* __restrict__ Wi,
                                                const float* __restrict__ Wh,
                                                const float* __restrict__ Wo,
                                                ushort* __restrict__ Wi_b,
                                                ushort* __restrict__ Wh_b,
                                                ushort* __restrict__ Wo_b) {
    const int h = blockIdx.x, t = threadIdx.x;
    for (int c = t; c < KWI; c += 256)
        Wi_b[h * KWI + c] = f2b(c < FD ? Wi[h * FD + c] : 0.f);
    for (int c = t; c < Hh; c += 256)
        Wh_b[h * Hh + c] = f2b(Wh[h * Hh + c]);
    for (int c = t; c < KWO; c += 256) {
        float v = 0.f;
        if (c < AFD)       v = Wo[h * CATD + c];
        else if (c >= 160) v = Wo[h * CATD + AFD + (c - 160)];
        Wo_b[h * KWO + c] = f2b(v);
    }
}

// ---------------------------------------------------------------------------
// Fused DMPNN: one block = one molecule, 1024 threads (16 waves).
// __launch_bounds__(1024, 1): empirically (R4/R6 VGPR counters) the 2nd arg
// acts as BLOCKS/CU on this toolchain -> 1 block/CU = 16 waves = 4 waves/EU
// -> 128-VGPR cap. (R6's (1024,4) meant 4 blocks/CU -> 8 waves/EU -> 64 VGPR
// -> ~300 MB spill traffic. Under either documented semantics, (1024,1)
// yields the 128 cap, since a 1024-thread block needs 4 waves/EU resident.)
// Phases 1-2: wave w owns bond rows [w*16, w*16+16): acc[8] (32 VGPR/AGPR),
// inp skip kept packed-bf16 in registers (16 VGPR).
// Phase 3: wave w = (strip, col-half): 16 atoms x 64 cols, racc[4].
// msg lives in XOR-swizzled LDS (64 KB); indices in registers; weights bf16
// from global (L1/L2-resident).
// ---------------------------------------------------------------------------
__global__ __launch_bounds__(1024, 1) void k_fused(
        const float* __restrict__ fini, const int* __restrict__ mapping,
        const int* __restrict__ a2ib, const float* __restrict__ atomf,
        const ushort* __restrict__ Wi_b, const ushort* __restrict__ Wh_b,
        const ushort* __restrict__ Wo_b, const float* __restrict__ bo,
        const int* __restrict__ mol_lens, const int* __restrict__ pfx,
        float* __restrict__ out) {
    __shared__ ushort sMsg[256 * 128];     // 64 KB, XOR-swizzled

    const int tid  = threadIdx.x;
    const int mol  = blockIdx.x;
    const int wave = tid >> 6, lane = tid & 63;
    const int l15  = lane & 15, quad = lane >> 4;

    // Row ownership + gather indices for phases 1-2
    const int mrow = wave * 16 + l15;                  // bond row
    int myMap[Kk];
#pragma unroll
    for (int k = 0; k < Kk; ++k)
        myMap[k] = mapping[((size_t)mol * Ee + mrow) * Kk + k];

    // ---------------- Phase 1: inp = fini @ Wi^T (K=147 -> 160) ------------
    f32x4 acc[8] = {};
    const float* frow = fini + ((size_t)mol * Ee + mrow) * FD;
#pragma unroll
    for (int ks = 0; ks < 5; ++ks) {
        bf16x8 af;
        const float* p = frow + ks * 32 + quad * 8;
        if (ks < 4 || quad < 2) {
            af = cvt8(*(const f4u*)p, *(const f4u*)(p + 4));
        } else if (quad == 2) {             // cols 144..146 real, rest zero
            union { uint4 u; bf16x8 v; } r;
            r.u.x = f2b2(p[0], p[1]);
            r.u.y = f2b2(p[2], 0.f);
            r.u.z = 0u; r.u.w = 0u;
            af = r.v;
        } else {
            af = zero8();
        }
#pragma unroll
        for (int j = 0; j < 8; ++j) {
            bf16x8 bf = *(const bf16x8*)&Wi_b[(j * 16 + l15) * KWI + ks * 32 + quad * 8];
            acc[j] = __builtin_amdgcn_mfma_f32_16x16x32_bf16(af, bf, acc[j], 0, 0, 0);
        }
    }

    // Keep inp packed bf16 in registers (C-layout); write relu(inp) to sMsg.
    uint2 inpP[8];
#pragma unroll
    for (int j = 0; j < 8; ++j) {
        inpP[j].x = f2b2(acc[j][0], acc[j][1]);
        inpP[j].y = f2b2(acc[j][2], acc[j][3]);
        const int col = j * 16 + l15;
#pragma unroll
        for (int reg = 0; reg < 4; ++reg) {
            const int row = wave * 16 + quad * 4 + reg;
            float v = acc[j][reg];
            sMsg[swz(row, col)] = f2b(v > 0.f ? v : 0.f);
        }
    }
    __syncthreads();

    // ---------------- Phase 2: two hops -------------------------------------
#pragma unroll 1
    for (int hop = 0; hop < 2; ++hop) {
#pragma unroll
        for (int j = 0; j < 8; ++j) acc[j] = f32x4{0.f, 0.f, 0.f, 0.f};

#pragma unroll
        for (int ks = 0; ks < 4; ++ks) {
            const int g = ks * 4 + quad;
            float s[8] = {0.f, 0.f, 0.f, 0.f, 0.f, 0.f, 0.f, 0.f};
#pragma unroll
            for (int kk = 0; kk < Kk; ++kk) {
                const int r = myMap[kk];
                uint4 m8 = *(const uint4*)&sMsg[r * 128 + ((g ^ (r & 7)) << 3)];
                acc_octet(s, m8);
            }
            bf16x8 af = pack8(s);
#pragma unroll
            for (int j = 0; j < 8; ++j) {
                bf16x8 bf = *(const bf16x8*)&Wh_b[(j * 16 + l15) * Hh + ks * 32 + quad * 8];
                acc[j] = __builtin_amdgcn_mfma_f32_16x16x32_bf16(af, bf, acc[j], 0, 0, 0);
            }
        }
        __syncthreads();                    // all gathers done before overwrite
#pragma unroll
        for (int j = 0; j < 8; ++j) {
            const int col = j * 16 + l15;
            float2 p01 = b2f2(inpP[j].x);
            float2 p23 = b2f2(inpP[j].y);
            float v[4] = {p01.x + acc[j][0], p01.y + acc[j][1],
                          p23.x + acc[j][2], p23.y + acc[j][3]};
#pragma unroll
            for (int reg = 0; reg < 4; ++reg) {
                const int row = wave * 16 + quad * 4 + reg;
                sMsg[swz(row, col)] = f2b(v[reg] > 0.f ? v[reg] : 0.f);
            }
        }
        __syncthreads();
    }

    // ---------------- Phase 3: readout --------------------------------------
    // K-space: [0,133) atomf (padded to 160), [160,288) m2a gather from sMsg.
    // Wave (aw, ch): 16 atoms x 64 cols; j4 = ch*4 + jj.
    const int aw   = wave & 7, ch = wave >> 3;
    const int arow = aw * 16 + l15;                    // atom row
    int myA2[Kk];                                      // loaded late (live-range)
#pragma unroll
    for (int k = 0; k < Kk; ++k)
        myA2[k] = a2ib[((size_t)mol * Aa + arow) * Kk + k];

    f32x4 racc[4] = {};
    const float* arow_p = atomf + ((size_t)mol * Aa + arow) * AFD;
#pragma unroll
    for (int ks = 0; ks < 9; ++ks) {
        bf16x8 af;
        if (ks < 4) {                               // atomf cols 0..127
            const float* p = arow_p + ks * 32 + quad * 8;
            af = cvt8(*(const f4u*)p, *(const f4u*)(p + 4));
        } else if (ks == 4) {                       // cols 128..132 real
            if (quad == 0) {
                const float* p = arow_p + 128;
                union { uint4 u; bf16x8 v; } r;
                r.u.x = f2b2(p[0], p[1]);
                r.u.y = f2b2(p[2], p[3]);
                r.u.z = f2b2(p[4], 0.f);
                r.u.w = 0u;
                af = r.v;
            } else {
                af = zero8();
            }
        } else {                                    // m2a gather
            const int g = (ks - 5) * 4 + quad;
            float s[8] = {0.f, 0.f, 0.f, 0.f, 0.f, 0.f, 0.f, 0.f};
#pragma unroll
            for (int kk = 0; kk < Kk; ++kk) {
                const int r = myA2[kk];
                uint4 m8 = *(const uint4*)&sMsg[r * 128 + ((g ^ (r & 7)) << 3)];
                acc_octet(s, m8);
            }
            af = pack8(s);
        }
#pragma unroll
        for (int jj = 0; jj < 4; ++jj) {
            const int j4 = ch * 4 + jj;
            bf16x8 bf = *(const bf16x8*)&Wo_b[(j4 * 16 + l15) * KWO + ks * 32 + quad * 8];
            racc[jj] = __builtin_amdgcn_mfma_f32_16x16x32_bf16(af, bf, racc[jj], 0, 0, 0);
        }
    }

    const int len  = mol_lens[mol];
    const int base = pfx[mol];
#pragma unroll
    for (int jj = 0; jj < 4; ++jj) {
        const int col = (ch * 4 + jj) * 16 + l15;
        const float bj = bo[col];
#pragma unroll
        for (int reg = 0; reg < 4; ++reg) {
            const int ar = aw * 16 + quad * 4 + reg;
            if (ar < len) {
                float v = racc[jj][reg] + bj;
                out[(size_t)(base + ar) * Hh + col] = v > 0.f ? v : 0.f;
            }
        }
    }
}

// ---------------------------------------------------------------------------
__global__ __launch_bounds__(512) void k_scan(const int* __restrict__ ml,
                                              int* __restrict__ pfx) {
    __shared__ int s[512];
    int t = threadIdx.x;
    s[t] = ml[t];
    __syncthreads();
    for (int off = 1; off < 512; off <<= 1) {
        int v = (t >= off) ? s[t - off] : 0;
        __syncthreads();
        s[t] += v;
        __syncthreads();
    }
    pfx[t + 1] = s[t];
    if (t == 0) pfx[0] = 0;
}

__global__ __launch_bounds__(128) void k_cmask(const int* __restrict__ ml,
                                               float* __restrict__ cmask) {
    int b = blockIdx.x, t = threadIdx.x;
    cmask[b * Aa + t] = (t < ml[b]) ? 1.0f : 0.0f;
}

// ---------------------------------------------------------------------------
extern "C" void kernel_launch(void* const* d_in, const int* in_sizes, int n_in,
                              void* d_out, int out_size, void* d_ws, size_t ws_size,
                              hipStream_t stream) {
    const float* atom_feature = (const float*)d_in[0];
    const float* f_ini        = (const float*)d_in[1];
    const int*   a2ib         = (const int*)d_in[2];
    const int*   mapping      = (const int*)d_in[3];
    const int*   mol_lens     = (const int*)d_in[5];
    const float* Wi           = (const float*)d_in[6];
    const float* Wh           = (const float*)d_in[7];
    const float* Wo           = (const float*)d_in[8];
    const float* bo           = (const float*)d_in[9];
    float* out = (float*)d_out;

    // Workspace: only prepped weights + prefix sums (~0.2 MB)
    ushort* Wi_b = (ushort*)d_ws;
    ushort* Wh_b = Wi_b + 128 * KWI;
    ushort* Wo_b = Wh_b + 128 * Hh;
    int*    pfx  = (int*)(Wo_b + 128 * KWO);

    float* cmask = out + ((size_t)out_size - (size_t)Bm * Aa);

    k_prep_w<<<128, 256, 0, stream>>>(Wi, Wh, Wo, Wi_b, Wh_b, Wo_b);
    k_scan  <<<1, 512, 0, stream>>>(mol_lens, pfx);
    k_cmask <<<Bm, 128, 0, stream>>>(mol_lens, cmask);
    k_fused <<<Bm, 1024, 0, stream>>>(f_ini, mapping, a2ib, atom_feature,
                                      Wi_b, Wh_b, Wo_b, bo, mol_lens, pfx, out);
}

// Round 8
// 349.440 us; speedup vs baseline: 1.1915x; 1.1331x over previous
//
#include <hip/hip_runtime.h>
#include <hip/hip_bf16.h>

typedef unsigned int   uint;
typedef unsigned short ushort;
typedef short bf16x8 __attribute__((ext_vector_type(8)));
typedef float f32x4  __attribute__((ext_vector_type(4)));
typedef float f4u    __attribute__((ext_vector_type(4), aligned(4)));  // align-4 float4

// Problem constants
constexpr int Bm   = 512;   // molecules
constexpr int Aa   = 128;   // atoms / molecule
constexpr int Ee   = 256;   // directed bonds / molecule
constexpr int Kk   = 6;     // incoming gathered
constexpr int AFD  = 133;
constexpr int FD   = 147;   // 133+14
constexpr int Hh   = 128;
constexpr int CATD = 261;   // 133+128
constexpr int KWI  = 160;   // Wi_b row stride (147 real + 13 zero)
constexpr int KWO  = 288;   // Wo_b row stride: [0,133) atomf cols, [133,160) zero, [160,288) m2a

// ---- bf16 helpers ----------------------------------------------------------
__device__ __forceinline__ ushort f2b(float f) {
    uint u = __float_as_uint(f);
    u += 0x7FFFu + ((u >> 16) & 1u);
    return (ushort)(u >> 16);
}
__device__ __forceinline__ uint f2b2(float x, float y) {
    return (uint)f2b(x) | ((uint)f2b(y) << 16);
}
__device__ __forceinline__ float2 b2f2(uint p) {
    float2 r;
    r.x = __uint_as_float(p << 16);
    r.y = __uint_as_float(p & 0xFFFF0000u);
    return r;
}
// relu on 2 packed bf16 (zero the halves whose sign bit is set)
__device__ __forceinline__ uint relu2u(uint u) {
    uint neg  = u & 0x80008000u;
    uint mask = (neg >> 15) * 0xFFFFu;
    return u & ~mask;
}
__device__ __forceinline__ bf16x8 cvt8(f4u a, f4u b) {
    union { uint4 u; bf16x8 v; } r;
    r.u.x = f2b2(a.x, a.y); r.u.y = f2b2(a.z, a.w);
    r.u.z = f2b2(b.x, b.y); r.u.w = f2b2(b.z, b.w);
    return r.v;
}
__device__ __forceinline__ bf16x8 zero8() {
    union { uint4 u; bf16x8 v; } r;
    r.u.x = r.u.y = r.u.z = r.u.w = 0u;
    return r.v;
}
__device__ __forceinline__ void acc_octet(float s[8], uint4 m8) {
    uint u0 = relu2u(m8.x), u1 = relu2u(m8.y), u2 = relu2u(m8.z), u3 = relu2u(m8.w);
    float2 a0 = b2f2(u0); s[0] += a0.x; s[1] += a0.y;
    float2 a1 = b2f2(u1); s[2] += a1.x; s[3] += a1.y;
    float2 a2 = b2f2(u2); s[4] += a2.x; s[5] += a2.y;
    float2 a3 = b2f2(u3); s[6] += a3.x; s[7] += a3.y;
}
__device__ __forceinline__ bf16x8 pack8(const float s[8]) {
    union { uint4 u; bf16x8 v; } r;
    r.u.x = f2b2(s[0], s[1]); r.u.y = f2b2(s[2], s[3]);
    r.u.z = f2b2(s[4], s[5]); r.u.w = f2b2(s[6], s[7]);
    return r.v;
}
// XOR-swizzled sMsg address (elements). Row-major 256x128, octet ^= row&7.
__device__ __forceinline__ int swz(int row, int col) {
    return row * 128 + ((((col >> 3) ^ (row & 7))) << 3) + (col & 7);
}

// ---------------------------------------------------------------------------
// Combined prep: weights -> padded bf16; block 0 also scans mol_lens; all
// blocks help write cmask. One launch instead of three.
// ---------------------------------------------------------------------------
__global__ __launch_bounds__(512) void k_prep(const float* __restrict__ Wi,
                                              const float* __restrict__ Wh,
                                              const float* __restrict__ Wo,
                                              const int* __restrict__ ml,
                                              ushort* __restrict__ Wi_b,
                                              ushort* __restrict__ Wh_b,
                                              ushort* __restrict__ Wo_b,
                                              int* __restrict__ pfx,
                                              float* __restrict__ cmask) {
    const int h = blockIdx.x, t = threadIdx.x;   // 128 blocks
    for (int c = t; c < KWI; c += 512)
        Wi_b[h * KWI + c] = f2b(c < FD ? Wi[h * FD + c] : 0.f);
    for (int c = t; c < Hh; c += 512)
        Wh_b[h * Hh + c] = f2b(Wh[h * Hh + c]);
    for (int c = t; c < KWO; c += 512) {
        float v = 0.f;
        if (c < AFD)       v = Wo[h * CATD + c];
        else if (c >= 160) v = Wo[h * CATD + AFD + (c - 160)];
        Wo_b[h * KWO + c] = f2b(v);
    }
    {   // cmask: block h covers molecules h*4 .. h*4+3
        const int m = h * 4 + (t >> 7), c = t & 127;
        cmask[m * Aa + c] = (c < ml[m]) ? 1.0f : 0.0f;
    }
    if (h == 0) {   // exclusive prefix sum over 512 mol_lens
        __shared__ int s[512];
        s[t] = ml[t];
        __syncthreads();
        for (int off = 1; off < 512; off <<= 1) {
            int v = (t >= off) ? s[t - off] : 0;
            __syncthreads();
            s[t] += v;
            __syncthreads();
        }
        pfx[t + 1] = s[t];
        if (t == 0) pfx[0] = 0;
    }
}

// ---------------------------------------------------------------------------
// Fused DMPNN: one block = one molecule, 512 threads (8 waves).
// amdgpu_waves_per_eu(2,2) pins 2 waves/EU -> 256 unified regs/wave (the
// launch_bounds 2nd arg only sets a FLOOR on waves/EU; R4/R6/R7 counters
// show the compiler's own occupancy pick capped regs at 128/64 -> 100-300 MB
// of scratch spill traffic. Pinning the MAX is the only way to get 256.)
// Exactly 1 block/CU resident (8 waves = 2/EU).
// Phases 1-2: wave w owns bond rows [w*32, w*32+32) as 2 strips of 16:
//   acc[2][8] (64 regs) + inpP[2][8] packed-bf16 skip (32 regs).
// Phase 3: wave w owns atom rows [w*16, w*16+16), full 128 cols: racc[8].
// msg in XOR-swizzled LDS (64 KB); gather indices in LDS; weights bf16 from
// global (L1/L2-resident, broadcast across lanes).
// ---------------------------------------------------------------------------
__global__ __attribute__((amdgpu_flat_work_group_size(512, 512),
                          amdgpu_waves_per_eu(2, 2))) void k_fused(
        const float* __restrict__ fini, const int* __restrict__ mapping,
        const int* __restrict__ a2ib, const float* __restrict__ atomf,
        const ushort* __restrict__ Wi_b, const ushort* __restrict__ Wh_b,
        const ushort* __restrict__ Wo_b, const float* __restrict__ bo,
        const int* __restrict__ mol_lens, const int* __restrict__ pfx,
        float* __restrict__ out) {
    __shared__ ushort sMsg[256 * 128];     // 64 KB, XOR-swizzled
    __shared__ int    sMap[256 * Kk];      // 6 KB
    __shared__ int    sA2[128 * Kk];       // 3 KB

    const int tid  = threadIdx.x;
    const int mol  = blockIdx.x;
    const int wave = tid >> 6, lane = tid & 63;
    const int l15  = lane & 15, quad = lane >> 4;

    for (int i = tid; i < 256 * Kk; i += 512) sMap[i] = mapping[(size_t)mol * 256 * Kk + i];
    for (int i = tid; i < 128 * Kk; i += 512) sA2[i]  = a2ib[(size_t)mol * 128 * Kk + i];

    // ---------------- Phase 1: inp = fini @ Wi^T (K=147 -> 160) ------------
    f32x4 acc[2][8] = {};
    const size_t bondBase = (size_t)mol * Ee;
#pragma unroll
    for (int ks = 0; ks < 5; ++ks) {
        bf16x8 af[2];
#pragma unroll
        for (int i = 0; i < 2; ++i) {
            const int m = wave * 32 + i * 16 + l15;
            const float* p = fini + (bondBase + m) * FD + ks * 32 + quad * 8;
            if (ks < 4 || quad < 2) {
                af[i] = cvt8(*(const f4u*)p, *(const f4u*)(p + 4));
            } else if (quad == 2) {         // cols 144..146 real, rest zero
                union { uint4 u; bf16x8 v; } r;
                r.u.x = f2b2(p[0], p[1]);
                r.u.y = f2b2(p[2], 0.f);
                r.u.z = 0u; r.u.w = 0u;
                af[i] = r.v;
            } else {
                af[i] = zero8();
            }
        }
#pragma unroll
        for (int j = 0; j < 8; ++j) {
            bf16x8 bf = *(const bf16x8*)&Wi_b[(j * 16 + l15) * KWI + ks * 32 + quad * 8];
            acc[0][j] = __builtin_amdgcn_mfma_f32_16x16x32_bf16(af[0], bf, acc[0][j], 0, 0, 0);
            acc[1][j] = __builtin_amdgcn_mfma_f32_16x16x32_bf16(af[1], bf, acc[1][j], 0, 0, 0);
        }
    }

    // Keep inp packed bf16 in registers (C-layout); write relu(inp) to sMsg.
    uint2 inpP[2][8];
#pragma unroll
    for (int i = 0; i < 2; ++i)
#pragma unroll
        for (int j = 0; j < 8; ++j) {
            inpP[i][j].x = f2b2(acc[i][j][0], acc[i][j][1]);
            inpP[i][j].y = f2b2(acc[i][j][2], acc[i][j][3]);
            const int col = j * 16 + l15;
#pragma unroll
            for (int reg = 0; reg < 4; ++reg) {
                const int row = wave * 32 + i * 16 + quad * 4 + reg;
                float v = acc[i][j][reg];
                sMsg[swz(row, col)] = f2b(v > 0.f ? v : 0.f);
            }
        }
    __syncthreads();

    // ---------------- Phase 2: two hops -------------------------------------
#pragma unroll 1
    for (int hop = 0; hop < 2; ++hop) {
#pragma unroll
        for (int i = 0; i < 2; ++i)
#pragma unroll
            for (int j = 0; j < 8; ++j)
                acc[i][j] = f32x4{0.f, 0.f, 0.f, 0.f};

#pragma unroll
        for (int ks = 0; ks < 4; ++ks) {
            bf16x8 af[2];
#pragma unroll
            for (int i = 0; i < 2; ++i) {
                const int m = wave * 32 + i * 16 + l15;
                const int* mp = &sMap[m * Kk];
                const int g = ks * 4 + quad;
                float s[8] = {0.f, 0.f, 0.f, 0.f, 0.f, 0.f, 0.f, 0.f};
#pragma unroll
                for (int kk = 0; kk < Kk; ++kk) {
                    const int r = mp[kk];
                    uint4 m8 = *(const uint4*)&sMsg[r * 128 + ((g ^ (r & 7)) << 3)];
                    acc_octet(s, m8);
                }
                af[i] = pack8(s);
            }
#pragma unroll
            for (int j = 0; j < 8; ++j) {
                bf16x8 bf = *(const bf16x8*)&Wh_b[(j * 16 + l15) * Hh + ks * 32 + quad * 8];
                acc[0][j] = __builtin_amdgcn_mfma_f32_16x16x32_bf16(af[0], bf, acc[0][j], 0, 0, 0);
                acc[1][j] = __builtin_amdgcn_mfma_f32_16x16x32_bf16(af[1], bf, acc[1][j], 0, 0, 0);
            }
        }
        __syncthreads();                    // all gathers done before overwrite
#pragma unroll
        for (int i = 0; i < 2; ++i)
#pragma unroll
            for (int j = 0; j < 8; ++j) {
                const int col = j * 16 + l15;
                float2 p01 = b2f2(inpP[i][j].x);
                float2 p23 = b2f2(inpP[i][j].y);
                float v[4] = {p01.x + acc[i][j][0], p01.y + acc[i][j][1],
                              p23.x + acc[i][j][2], p23.y + acc[i][j][3]};
#pragma unroll
                for (int reg = 0; reg < 4; ++reg) {
                    const int row = wave * 32 + i * 16 + quad * 4 + reg;
                    sMsg[swz(row, col)] = f2b(v[reg] > 0.f ? v[reg] : 0.f);
                }
            }
        __syncthreads();
    }

    // ---------------- Phase 3: readout --------------------------------------
    // K-space: [0,133) atomf (padded to 160), [160,288) m2a gather from sMsg.
    f32x4 racc[8] = {};
    const int a = wave * 16 + l15;                  // atom row in molecule
    const size_t arow = (size_t)mol * Aa + a;
#pragma unroll
    for (int ks = 0; ks < 9; ++ks) {
        bf16x8 af;
        if (ks < 4) {                               // atomf cols 0..127
            const float* p = atomf + arow * AFD + ks * 32 + quad * 8;
            af = cvt8(*(const f4u*)p, *(const f4u*)(p + 4));
        } else if (ks == 4) {                       // cols 128..132 real
            if (quad == 0) {
                const float* p = atomf + arow * AFD + 128;
                union { uint4 u; bf16x8 v; } r;
                r.u.x = f2b2(p[0], p[1]);
                r.u.y = f2b2(p[2], p[3]);
                r.u.z = f2b2(p[4], 0.f);
                r.u.w = 0u;
                af = r.v;
            } else {
                af = zero8();
            }
        } else {                                    // m2a gather
            const int* ap = &sA2[a * Kk];
            const int g = (ks - 5) * 4 + quad;
            float s[8] = {0.f, 0.f, 0.f, 0.f, 0.f, 0.f, 0.f, 0.f};
#pragma unroll
            for (int kk = 0; kk < Kk; ++kk) {
                const int r = ap[kk];
                uint4 m8 = *(const uint4*)&sMsg[r * 128 + ((g ^ (r & 7)) << 3)];
                acc_octet(s, m8);
            }
            af = pack8(s);
        }
#pragma unroll
        for (int j = 0; j < 8; ++j) {
            bf16x8 bf = *(const bf16x8*)&Wo_b[(j * 16 + l15) * KWO + ks * 32 + quad * 8];
            racc[j] = __builtin_amdgcn_mfma_f32_16x16x32_bf16(af, bf, racc[j], 0, 0, 0);
        }
    }

    const int len  = mol_lens[mol];
    const int base = pfx[mol];
#pragma unroll
    for (int j = 0; j < 8; ++j) {
        const int col = j * 16 + l15;
        const float bj = bo[col];
#pragma unroll
        for (int reg = 0; reg < 4; ++reg) {
            const int ar = wave * 16 + quad * 4 + reg;
            if (ar < len) {
                float v = racc[j][reg] + bj;
                out[(size_t)(base + ar) * Hh + col] = v > 0.f ? v : 0.f;
            }
        }
    }
}

// ---------------------------------------------------------------------------
extern "C" void kernel_launch(void* const* d_in, const int* in_sizes, int n_in,
                              void* d_out, int out_size, void* d_ws, size_t ws_size,
                              hipStream_t stream) {
    const float* atom_feature = (const float*)d_in[0];
    const float* f_ini        = (const float*)d_in[1];
    const int*   a2ib         = (const int*)d_in[2];
    const int*   mapping      = (const int*)d_in[3];
    const int*   mol_lens     = (const int*)d_in[5];
    const float* Wi           = (const float*)d_in[6];
    const float* Wh           = (const float*)d_in[7];
    const float* Wo           = (const float*)d_in[8];
    const float* bo           = (const float*)d_in[9];
    float* out = (float*)d_out;

    // Workspace: only prepped weights + prefix sums (~0.2 MB)
    ushort* Wi_b = (ushort*)d_ws;
    ushort* Wh_b = Wi_b + 128 * KWI;
    ushort* Wo_b = Wh_b + 128 * Hh;
    int*    pfx  = (int*)(Wo_b + 128 * KWO);

    float* cmask = out + ((size_t)out_size - (size_t)Bm * Aa);

    k_prep <<<128, 512, 0, stream>>>(Wi, Wh, Wo, mol_lens,
                                     Wi_b, Wh_b, Wo_b, pfx, cmask);
    k_fused<<<Bm, 512, 0, stream>>>(f_ini, mapping, a2ib, atom_feature,
                                    Wi_b, Wh_b, Wo_b, bo, mol_lens, pfx, out);
}